// Round 13
// baseline (78.375 us; speedup 1.0000x reference)
//
#include <hip/hip_runtime.h>

// channel_attention: the attention branch is the identity (softmax over m
// sums to 1 in einsum 'bdct,bdcm->bdct'). Output = LN_c(pW @ x + pb) per
// (b,d,t) column.
//
// R12 = R8/R11 dataflow + T3/T4 counted-vmcnt pipeline. Each block owns 4
// consecutive t-tiles of one bd, double-buffered in LDS (2x32KB). Per wave:
//   DMA0,DMA1 | vm(8)+bar | C0 | lgkm+bar | ST0,DMA2 | vm(16)+bar | C1 |
//   lgkm+bar | ST1,DMA3 | vm(16)+bar | C2 | lgkm+bar | ST2 | vm(8)+bar |
//   C3 | lgkm+bar | ST3
// -> loads of tile i+2 in flight across stores(i)+compute(i+1): reads and
// writes mix on DRAM instead of R8's phase-locked alternation (__syncthreads
// vmcnt(0)-drains). Raw s_barrier + hand-counted vmcnt; Pf staged to LDS so
// loop vm counts are exactly {8 ST, 8 DMA}/tile. Wave-private rows (DMA &
// store) / wave-private columns (compute & y-writeback) keep 2 barriers/tile.

#define CC      64
#define TT      3000
#define TILE_T  128
#define TPB     4             // tiles per block
#define BPD     6             // blocks per bd (24 tiles / 4)
#define NWG     (256 * BPD)   // 1536 blocks, % 8 == 0 -> bijective swizzle
#define CPX     (NWG / 8)     // 192

typedef __attribute__((ext_vector_type(8)))  short short8;
typedef __attribute__((ext_vector_type(16))) float f32x16;
typedef __attribute__((ext_vector_type(4)))  float f32x4;

static __device__ __forceinline__ unsigned f2bf(float f) {
    unsigned u = __builtin_bit_cast(unsigned, f);
    return (u + 0x7FFFu + ((u >> 16) & 1u)) >> 16;
}

static __device__ __forceinline__ void load_lds16(const float* g, float* lds) {
    // 16B-per-lane DMA: LDS dest = wave-uniform base + lane*16 (verified R11).
    __builtin_amdgcn_global_load_lds(
        (const __attribute__((address_space(1))) unsigned*)g,
        (__attribute__((address_space(3))) unsigned*)lds, 16, 0, 0);
}

#define WAIT_VM_BAR(N)                                              \
    asm volatile("s_waitcnt vmcnt(" #N ")" ::: "memory");           \
    __builtin_amdgcn_sched_barrier(0);                              \
    __builtin_amdgcn_s_barrier()

#define WAIT_LGKM_BAR()                                             \
    asm volatile("s_waitcnt lgkmcnt(0)" ::: "memory");              \
    __builtin_amdgcn_sched_barrier(0);                              \
    __builtin_amdgcn_s_barrier()

// ws layout: Wf = 4096 shorts (8 KB); Pf = 192 floats at +8192 B.
// Wf[((ct*4+kc)*64 + lane)*8 + e] = bf16(pW[co*CC + c]),
//   co = ct*32 + (lane&31), c = kc*16 + (lane>>5)*8 + e.
// Pf[a*64 + (ct*2+half)*16 + r] = {pb,pg,pbeta}[ct*32 + half*4 + (r&3) + 8*(r>>2)]
__global__ void pack_params(const float* __restrict__ pW,
                            const float* __restrict__ pb,
                            const float* __restrict__ pg,
                            const float* __restrict__ pbeta,
                            short* __restrict__ Wf, float* __restrict__ Pf)
{
    int i = blockIdx.x * 256 + threadIdx.x;
    if (i < 4096) {
        int e = i & 7, l = (i >> 3) & 63, f = i >> 9;
        int ct = f >> 2, kc = f & 3;
        int co = ct * 32 + (l & 31);
        int c  = kc * 16 + (l >> 5) * 8 + e;
        Wf[i] = (short)f2bf(pW[co * CC + c]);
    } else if (i < 4096 + 192) {
        int j = i - 4096;
        int a = j >> 6, q = j & 63;
        int r = q & 15, half = (q >> 4) & 1, ct = q >> 5;
        int co = ct * 32 + half * 4 + (r & 3) + 8 * (r >> 2);
        const float* src = (a == 0) ? pb : (a == 1) ? pg : pbeta;
        Pf[j] = src[co];
    }
}

__global__ __launch_bounds__(256, 2) void fused_mfma_ln(
    const float* __restrict__ x,    // [BD, CC, TT]
    const short* __restrict__ Wf,
    const float* __restrict__ Pf,
    float* __restrict__ out)        // [BD, CC, TT]
{
    __shared__ float xy[2][CC * TILE_T];   // 2 x 32 KB double buffer
    __shared__ float pfl[192];             // Pf mirror (keeps loop vm-clean)

    const int bid  = blockIdx.x;
    const int swz  = (bid & 7) * CPX + (bid >> 3);   // XCD-chunked, bijective
    const int bd   = swz / BPD;
    const int tseg = swz - bd * BPD;
    const int t00  = tseg * (TPB * TILE_T);          // base t of tile 0

    const int tid  = threadIdx.x;
    const int lane = tid & 63;
    const int wid  = tid >> 6;
    const int col  = lane & 31;
    const int half = lane >> 5;

    const size_t xbase = (size_t)bd * (CC * TT);

    // ---- Prologue: Pf -> LDS (vm+ds, older than every wait target).
    if (tid < 192) pfl[tid] = Pf[tid];

    // W fragments (8 x 16B, L2-hot).
    short8 aW[2][4];
#pragma unroll
    for (int ct = 0; ct < 2; ++ct)
#pragma unroll
        for (int kc = 0; kc < 4; ++kc)
            aW[ct][kc] = ((const short8*)Wf)[(ct * 4 + kc) * 64 + lane];

    // DMA one tile into buf: instr r covers rows c0=r*8+wid*2 (+1 for upper
    // half-wave) -- wave-private rows, per-lane global addr (as R11).
    auto DMASTAGE = [&](float* buf, int t0b) {
        int tq = t0b + col * 4;
        if (tq > TT - 4) tq = TT - 4;   // tail clamp (dup, never stored)
#pragma unroll
        for (int r = 0; r < 8; ++r) {
            const int c  = r * 8 + wid * 2 + half;
            const int c0 = r * 8 + wid * 2;
            load_lds16(x + xbase + (size_t)c * TT + tq, &buf[c0 * TILE_T]);
        }
    };

    // Phases 2-4: MFMA + bias + LN + y-writeback (wave-private columns).
    auto COMPUTE = [&](float* buf) {
        const int tcol = wid * 32 + col;
        short8 bx[4];
#pragma unroll
        for (int kc = 0; kc < 4; ++kc) {
            union { unsigned u[4]; short8 s; } cvt;
#pragma unroll
            for (int p = 0; p < 4; ++p) {
                const float a = buf[(kc * 16 + half * 8 + 2 * p)     * TILE_T + tcol];
                const float b = buf[(kc * 16 + half * 8 + 2 * p + 1) * TILE_T + tcol];
                cvt.u[p] = f2bf(a) | (f2bf(b) << 16);
            }
            bx[kc] = cvt.s;
        }
        f32x16 acc[2];
#pragma unroll
        for (int r = 0; r < 16; ++r) { acc[0][r] = 0.0f; acc[1][r] = 0.0f; }
#pragma unroll
        for (int kc = 0; kc < 4; ++kc) {
            acc[0] = __builtin_amdgcn_mfma_f32_32x32x16_bf16(aW[0][kc], bx[kc], acc[0], 0, 0, 0);
            acc[1] = __builtin_amdgcn_mfma_f32_32x32x16_bf16(aW[1][kc], bx[kc], acc[1], 0, 0, 0);
        }
        float s = 0.0f, s2 = 0.0f;
#pragma unroll
        for (int ct = 0; ct < 2; ++ct) {
            const float4* pbv = (const float4*)(pfl + (ct * 2 + half) * 16);
#pragma unroll
            for (int q = 0; q < 4; ++q) {
                const float4 b4 = pbv[q];
                acc[ct][q * 4 + 0] += b4.x;
                acc[ct][q * 4 + 1] += b4.y;
                acc[ct][q * 4 + 2] += b4.z;
                acc[ct][q * 4 + 3] += b4.w;
            }
#pragma unroll
            for (int r = 0; r < 16; ++r) {
                const float v = acc[ct][r];
                s += v;
                s2 = fmaf(v, v, s2);
            }
        }
        s  += __shfl_xor(s, 32);
        s2 += __shfl_xor(s2, 32);
        const float mu   = s * (1.0f / CC);
        const float rstd = rsqrtf(s2 * (1.0f / CC) - mu * mu + 1e-5f);
#pragma unroll
        for (int ct = 0; ct < 2; ++ct) {
            const float4* pgv = (const float4*)(pfl + 64  + (ct * 2 + half) * 16);
            const float4* pev = (const float4*)(pfl + 128 + (ct * 2 + half) * 16);
#pragma unroll
            for (int q = 0; q < 4; ++q) {
                const float4 g4 = pgv[q];
                const float4 e4 = pev[q];
                const float gg[4] = {g4.x, g4.y, g4.z, g4.w};
                const float ee[4] = {e4.x, e4.y, e4.z, e4.w};
#pragma unroll
                for (int j = 0; j < 4; ++j) {
                    const int r  = q * 4 + j;
                    const int co = ct * 32 + half * 4 + (r & 3) + 8 * (r >> 2);
                    buf[co * TILE_T + tcol] = (acc[ct][r] - mu) * rstd * gg[j] + ee[j];
                }
            }
        }
    };

    // Phase 5: read wave-private rows to regs, drain lgkm, 8 NT stores.
    // (lgkm drain also makes the same-buffer DMA issued right after safe.)
    auto TSTORE = [&](const float* buf, int t0b) {
        f32x4 v[8];
#pragma unroll
        for (int r = 0; r < 8; ++r) {
            const int c = r * 8 + wid * 2 + half;
            v[r] = *(const f32x4*)&buf[c * TILE_T + col * 4];
        }
        asm volatile("s_waitcnt lgkmcnt(0)" ::: "memory");
        __builtin_amdgcn_sched_barrier(0);
        const bool stok = (t0b + col * 4) < TT;
#pragma unroll
        for (int r = 0; r < 8; ++r) {
            const int c = r * 8 + wid * 2 + half;
            if (stok)
                __builtin_nontemporal_store(
                    v[r], (f32x4*)(out + xbase + (size_t)c * TT + t0b + col * 4));
        }
    };

    // ---- Pipeline over 4 tiles.
    DMASTAGE(xy[0], t00);
    DMASTAGE(xy[1], t00 + TILE_T);
    asm volatile("s_waitcnt vmcnt(8) lgkmcnt(0)" ::: "memory");  // DMA0 + pfl
    __builtin_amdgcn_sched_barrier(0);
    __builtin_amdgcn_s_barrier();

    COMPUTE(xy[0]);
    WAIT_LGKM_BAR();
    TSTORE(xy[0], t00);  DMASTAGE(xy[0], t00 + 2 * TILE_T);
    WAIT_VM_BAR(16);                 // DMA1 done (ST0+DMA2 remain)

    COMPUTE(xy[1]);
    WAIT_LGKM_BAR();
    TSTORE(xy[1], t00 + TILE_T);  DMASTAGE(xy[1], t00 + 3 * TILE_T);
    WAIT_VM_BAR(16);                 // DMA2 done (ST1+DMA3 remain)

    COMPUTE(xy[0]);
    WAIT_LGKM_BAR();
    TSTORE(xy[0], t00 + 2 * TILE_T);
    WAIT_VM_BAR(8);                  // DMA3 done (ST2 remains)

    COMPUTE(xy[1]);
    WAIT_LGKM_BAR();
    TSTORE(xy[1], t00 + 3 * TILE_T);
    // endpgm drains remaining stores.
}

extern "C" void kernel_launch(void* const* d_in, const int* in_sizes, int n_in,
                              void* d_out, int out_size, void* d_ws, size_t ws_size,
                              hipStream_t stream) {
    // setup_inputs order: x, qW, qb, qg, qbeta, kW, kb, kg, kbeta, pW, pb, pg, pbeta
    const float* x     = (const float*)d_in[0];
    const float* pW    = (const float*)d_in[9];
    const float* pb    = (const float*)d_in[10];
    const float* pg    = (const float*)d_in[11];
    const float* pbeta = (const float*)d_in[12];
    float* out = (float*)d_out;

    short* Wf = (short*)d_ws;                          // 8 KB
    float* Pf = (float*)((char*)d_ws + 8192);          // 768 B

    pack_params<<<17, 256, 0, stream>>>(pW, pb, pg, pbeta, Wf, Pf);

    dim3 grid(NWG);         // 1536 blocks
    dim3 block(256);
    fused_mfma_ln<<<grid, block, 0, stream>>>(x, Wf, Pf, out);
}

// Round 14
// 67.801 us; speedup vs baseline: 1.1560x; 1.1560x over previous
//
#include <hip/hip_runtime.h>

// channel_attention: the attention branch is the identity (softmax over m
// sums to 1 in einsum 'bdct,bdcm->bdct'). Output = LN_c(pW @ x + pb) per
// (b,d,t) column.
//
// R13 = R8 exactly (measured best: 67.4us, ~4.4 TB/s effective).
// Probed and falsified around this point: occupancy 6blk/CU (R10, write
// amplification), 1KB segments (R7, write amplification), sc0sc1nt L3
// bypass (R9, no FETCH change + slower), global_load_lds DMA (R11,
// neutral), counted-vmcnt cross-tile pipeline (R12, regressed -- 4
// independent blocks/CU already mix read/write on DRAM; 2 blk/CU lost
// more). Structure: f32 LDS tile [64][128], float4 loads (512B/row),
// MFMA 32x32x16 bf16 (W frags preloaded), LN epilogue on C/D layout,
// y back into same LDS, builtin-nontemporal float4 stores (512B/row).

#define CC      64
#define TT      3000
#define TILE_T  128
#define NTB     24            // ceil(TT / TILE_T)
#define NWG     (256 * NTB)   // 6144 blocks, % 8 == 0 -> bijective swizzle
#define CPX     (NWG / 8)     // 768

typedef __attribute__((ext_vector_type(8)))  short short8;
typedef __attribute__((ext_vector_type(16))) float f32x16;
typedef __attribute__((ext_vector_type(4)))  float f32x4;

static __device__ __forceinline__ unsigned f2bf(float f) {
    // round-to-nearest-even f32 -> bf16 (inputs finite)
    unsigned u = __builtin_bit_cast(unsigned, f);
    return (u + 0x7FFFu + ((u >> 16) & 1u)) >> 16;
}

// ws layout: Wf = 4096 shorts (8 KB); Pf = 192 floats at +8192 B.
// Wf[((ct*4+kc)*64 + lane)*8 + e] = bf16(pW[co*CC + c]),
//   co = ct*32 + (lane&31), c = kc*16 + (lane>>5)*8 + e.
// Pf[a*64 + (ct*2+half)*16 + r] = {pb,pg,pbeta}[ct*32 + half*4 + (r&3) + 8*(r>>2)]
__global__ void pack_params(const float* __restrict__ pW,
                            const float* __restrict__ pb,
                            const float* __restrict__ pg,
                            const float* __restrict__ pbeta,
                            short* __restrict__ Wf, float* __restrict__ Pf)
{
    int i = blockIdx.x * 256 + threadIdx.x;
    if (i < 4096) {
        int e = i & 7, l = (i >> 3) & 63, f = i >> 9;
        int ct = f >> 2, kc = f & 3;
        int co = ct * 32 + (l & 31);
        int c  = kc * 16 + (l >> 5) * 8 + e;
        Wf[i] = (short)f2bf(pW[co * CC + c]);
    } else if (i < 4096 + 192) {
        int j = i - 4096;
        int a = j >> 6, q = j & 63;
        int r = q & 15, half = (q >> 4) & 1, ct = q >> 5;
        int co = ct * 32 + half * 4 + (r & 3) + 8 * (r >> 2);
        const float* src = (a == 0) ? pb : (a == 1) ? pg : pbeta;
        Pf[j] = src[co];
    }
}

__global__ __launch_bounds__(256, 4) void fused_mfma_ln(
    const float* __restrict__ x,    // [BD, CC, TT]
    const short* __restrict__ Wf,
    const float* __restrict__ Pf,
    float* __restrict__ out)        // [BD, CC, TT]
{
    __shared__ float xy[CC * TILE_T];   // 32 KB, [c][t] f32; reused for y

    const int bid = blockIdx.x;
    const int swz = (bid & 7) * CPX + (bid >> 3);   // XCD-chunked, bijective
    const int bd  = swz / NTB;
    const int tb  = swz - bd * NTB;
    const int t0b = tb * TILE_T;

    const int tid  = threadIdx.x;
    const int lane = tid & 63;
    const int wid  = tid >> 6;
    const int col  = lane & 31;
    const int half = lane >> 5;

    const size_t xbase = (size_t)bd * (CC * TT);

    // W fragments: 8 x 16B loads, issued first to overlap with staging.
    short8 aW[2][4];
#pragma unroll
    for (int ct = 0; ct < 2; ++ct)
#pragma unroll
        for (int kc = 0; kc < 4; ++kc)
            aW[ct][kc] = ((const short8*)Wf)[(ct * 4 + kc) * 64 + lane];

    // ---- Phase 1: stage x[64][128] f32 -> LDS via float4 (512B/row segs).
    // round r: lanes 0-31 cover row c (full 128-t span), lanes 32-63 row c+1.
    int tq = t0b + col * 4;
    if (tq > TT - 4) tq = TT - 4;       // tail clamp (dup data, never stored)
    float4 tmp[8];
#pragma unroll
    for (int r = 0; r < 8; ++r) {
        const int c = r * 8 + wid * 2 + half;
        tmp[r] = *(const float4*)(x + xbase + (size_t)c * TT + tq);
    }
#pragma unroll
    for (int r = 0; r < 8; ++r) {
        const int c = r * 8 + wid * 2 + half;
        *(float4*)&xy[c * TILE_T + col * 4] = tmp[r];   // b128, conflict-free
    }
    __syncthreads();

    // ---- Phase 2: B-frags from LDS (b32 reads, lanes stride 4B: free),
    // pack to bf16. Same (kc, half, e)->c rule as aW -> permutation cancels.
    const int tcol = wid * 32 + col;    // this wave's 32 columns
    short8 bx[4];
#pragma unroll
    for (int kc = 0; kc < 4; ++kc) {
        union { unsigned u[4]; short8 s; } cvt;
#pragma unroll
        for (int p = 0; p < 4; ++p) {
            const float a = xy[(kc * 16 + half * 8 + 2 * p)     * TILE_T + tcol];
            const float b = xy[(kc * 16 + half * 8 + 2 * p + 1) * TILE_T + tcol];
            cvt.u[p] = f2bf(a) | (f2bf(b) << 16);
        }
        bx[kc] = cvt.s;
    }

    f32x16 acc[2];
#pragma unroll
    for (int r = 0; r < 16; ++r) { acc[0][r] = 0.0f; acc[1][r] = 0.0f; }
#pragma unroll
    for (int kc = 0; kc < 4; ++kc) {
        acc[0] = __builtin_amdgcn_mfma_f32_32x32x16_bf16(aW[0][kc], bx[kc], acc[0], 0, 0, 0);
        acc[1] = __builtin_amdgcn_mfma_f32_32x32x16_bf16(aW[1][kc], bx[kc], acc[1], 0, 0, 0);
    }

    // ---- Phase 3: bias + LN stats (C/D layout: col=lane&31,
    // row = ct*32 + half*4 + (r&3) + 8*(r>>2)); shfl_xor(32) joins halves.
    float s = 0.0f, s2 = 0.0f;
#pragma unroll
    for (int ct = 0; ct < 2; ++ct) {
        const float4* pbv = (const float4*)(Pf + (ct * 2 + half) * 16);
#pragma unroll
        for (int q = 0; q < 4; ++q) {
            const float4 b4 = pbv[q];
            acc[ct][q * 4 + 0] += b4.x;
            acc[ct][q * 4 + 1] += b4.y;
            acc[ct][q * 4 + 2] += b4.z;
            acc[ct][q * 4 + 3] += b4.w;
        }
#pragma unroll
        for (int r = 0; r < 16; ++r) {
            const float v = acc[ct][r];
            s += v;
            s2 = fmaf(v, v, s2);
        }
    }
    s  += __shfl_xor(s, 32);
    s2 += __shfl_xor(s2, 32);
    const float mu   = s * (1.0f / CC);
    const float rstd = rsqrtf(s2 * (1.0f / CC) - mu * mu + 1e-5f);

    // ---- Phase 4: write final outputs back into the SAME LDS buffer.
    // Wave w touches only its own 32 columns -> safe aliasing, one barrier.
#pragma unroll
    for (int ct = 0; ct < 2; ++ct) {
        const float4* pgv = (const float4*)(Pf + 64  + (ct * 2 + half) * 16);
        const float4* pev = (const float4*)(Pf + 128 + (ct * 2 + half) * 16);
#pragma unroll
        for (int q = 0; q < 4; ++q) {
            const float4 g4 = pgv[q];
            const float4 e4 = pev[q];
            const float gg[4] = {g4.x, g4.y, g4.z, g4.w};
            const float ee[4] = {e4.x, e4.y, e4.z, e4.w};
#pragma unroll
            for (int j = 0; j < 4; ++j) {
                const int r  = q * 4 + j;
                const int co = ct * 32 + half * 4 + (r & 3) + 8 * (r >> 2);
                xy[co * TILE_T + tcol] = (acc[ct][r] - mu) * rstd * gg[j] + ee[j];
            }
        }
    }
    __syncthreads();

    // ---- Phase 5: vectorized NON-TEMPORAL stores (evict-first: out has no
    // reuse; keep L3 for x). Mirror of phase 1 (512B/row segments).
    const bool stok = (t0b + col * 4) < TT;   // quad-aligned (TT % 4 == 0)
#pragma unroll
    for (int r = 0; r < 8; ++r) {
        const int c = r * 8 + wid * 2 + half;
        const f32x4 v = *(const f32x4*)&xy[c * TILE_T + col * 4];
        if (stok)
            __builtin_nontemporal_store(
                v, (f32x4*)(out + xbase + (size_t)c * TT + t0b + col * 4));
    }
}

extern "C" void kernel_launch(void* const* d_in, const int* in_sizes, int n_in,
                              void* d_out, int out_size, void* d_ws, size_t ws_size,
                              hipStream_t stream) {
    // setup_inputs order: x, qW, qb, qg, qbeta, kW, kb, kg, kbeta, pW, pb, pg, pbeta
    const float* x     = (const float*)d_in[0];
    const float* pW    = (const float*)d_in[9];
    const float* pb    = (const float*)d_in[10];
    const float* pg    = (const float*)d_in[11];
    const float* pbeta = (const float*)d_in[12];
    float* out = (float*)d_out;

    short* Wf = (short*)d_ws;                          // 8 KB
    float* Pf = (float*)((char*)d_ws + 8192);          // 768 B

    pack_params<<<17, 256, 0, stream>>>(pW, pb, pg, pbeta, Wf, Pf);

    dim3 grid(NWG);         // 6144 blocks
    dim3 block(256);
    fused_mfma_ln<<<grid, block, 0, stream>>>(x, Wf, Pf, out);
}